// Round 9
// baseline (515.828 us; speedup 1.0000x reference)
//
#include <hip/hip_runtime.h>

#define BATCH 1024
#define TSEQ  512
#define DIN   64
#define H     128
#define NCLS  10
#define BM    16
#define NTHREADS 256   /* 4 waves, 1 per SIMD: no phase-fighting on the pipes */

typedef _Float16 h16;
typedef __attribute__((ext_vector_type(2))) _Float16 half2v;
typedef __attribute__((ext_vector_type(4))) _Float16 half4v;
typedef __attribute__((ext_vector_type(8))) _Float16 half8v;
typedef __attribute__((ext_vector_type(2))) float f32x2;
typedef __attribute__((ext_vector_type(4))) float f32x4;

// Swizzled staging layout (units: halfs) for a 16-row x K-col fp16 tile.
// chunk(m, kg) = kg*16 + (m ^ (kg&7)); element (m,k) at chunk*8 + (k&7).
// A-frag read: lane(ln,grp) reads chunk(ln, 4s+grp) as one aligned b128;
// 64 distinct chunks per instr -> conflict-free. Writes spread by XOR.
__device__ __forceinline__ int stg_addr(int m, int k) {
    const int kg = k >> 3;
    return (((kg << 4) + (m ^ (kg & 7))) << 3) + (k & 7);
}

#define SCALE_G (-2.8853900817779268f)   /* -2*log2(e): tanh gates */
#define SCALE_S (-1.4426950408889634f)   /* -log2(e):   sigmoid gates */

#define MFMA16(A, B, C) __builtin_amdgcn_mfma_f32_16x16x32_f16((A), (B), (C), 0, 0, 0)

// Persistent LSTM: 64 blocks x 16 batch rows, 4 waves/block (1 wave/SIMD).
// Wave w owns gate columns [32w,32w+32) (two 16-col n-tiles) of all 4
// gates -> c/h update register-local. Weights in registers/AGPRs as
// scale-folded fp16 B-fragments (~320 regs/wave; 1 wave/SIMD budget 512).
// Single wave per SIMD: MFMA and VALU overlap via within-wave ILP
// (independent streams: c-math || o-chain, h-math || x-GEMM(t+1)).
// Gate math fused over common denominators (7 trans/element):
//   c' = [c*(1+e_g)(1+e_i) + (1-e_g)(1+e_f)] / [(1+e_g)(1+e_i)(1+e_f)]
//   h  = (1-e_c) / ((1+e_c)(1+e_o)),  e_c = exp2(min(c'*SCALE_G, 126))
__global__ __launch_bounds__(NTHREADS, 1)
void lstm_persist(const float* __restrict__ x,
                  const float* __restrict__ Wgx, const float* __restrict__ Wgh,
                  const float* __restrict__ Wix, const float* __restrict__ Wih,
                  const float* __restrict__ Wfx, const float* __restrict__ Wfh,
                  const float* __restrict__ Wox, const float* __restrict__ Woh,
                  const float* __restrict__ Wph,
                  const float* __restrict__ bg, const float* __restrict__ bi,
                  const float* __restrict__ bfg, const float* __restrict__ bo,
                  const float* __restrict__ bp,
                  float* __restrict__ out)
{
    __shared__ __align__(16) h16 hbuf[2][H * BM];    // 2 x 4KB
    __shared__ __align__(16) h16 xbuf[2][DIN * BM];  // 2 x 2KB

    const int tid  = threadIdx.x;
    const int wave = tid >> 6;           // 0..3
    const int lane = tid & 63;
    const int grp  = lane >> 4;
    const int ln   = lane & 15;
    const int b0   = blockIdx.x * BM;
    const int n0   = (wave << 5) + ln;   // first n-tile column
    const int n1   = n0 + 16;            // second n-tile column

    // ---- weights -> register B-fragments (fp32 -> fp16, scale folded)
    half8v bx[4][2][2];     // [gate][kslice][ntile]
    half8v bh[4][4][2];
    f32x4  bias_c[4][2];
    {
        const float* WX[4] = {Wgx, Wix, Wfx, Wox};
        const float* WH[4] = {Wgh, Wih, Wfh, Woh};
        const float* BB[4] = {bg, bi, bfg, bo};
        const float  SC[4] = {SCALE_G, SCALE_S, SCALE_S, SCALE_S};
        const int    nn[2] = {n0, n1};
        #pragma unroll
        for (int G = 0; G < 4; ++G) {
            #pragma unroll
            for (int nt = 0; nt < 2; ++nt) {
                #pragma unroll
                for (int s = 0; s < 2; ++s) {
                    half8v v;
                    #pragma unroll
                    for (int j = 0; j < 8; ++j)
                        v[j] = (h16)(WX[G][(32*s + 8*grp + j) * H + nn[nt]] * SC[G]);
                    bx[G][s][nt] = v;
                }
                #pragma unroll
                for (int s = 0; s < 4; ++s) {
                    half8v v;
                    #pragma unroll
                    for (int j = 0; j < 8; ++j)
                        v[j] = (h16)(WH[G][(32*s + 8*grp + j) * H + nn[nt]] * SC[G]);
                    bh[G][s][nt] = v;
                }
                const float bb = BB[G][nn[nt]] * SC[G];
                bias_c[G][nt] = (f32x4){bb, bb, bb, bb};
            }
        }
    }

    // ---- hoisted LDS addresses (A-side identical for every wave)
    const int ha0 = stg_addr(ln,      8 * grp);
    const int ha1 = stg_addr(ln, 32 + 8 * grp);
    const int ha2 = stg_addr(ln, 64 + 8 * grp);
    const int ha3 = stg_addr(ln, 96 + 8 * grp);
    const int xa0 = ha0;
    const int xa1 = ha1;
    int hwr[2][4];
    #pragma unroll
    for (int r = 0; r < 4; ++r) {
        hwr[0][r] = stg_addr((grp << 2) + r, n0);
        hwr[1][r] = stg_addr((grp << 2) + r, n1);
    }

    // ---- x stager: 256 threads, 4 floats (16B) each
    const int xm  = tid >> 4;             // row 0..15
    const int xk0 = (tid & 15) << 2;      // k 0,4,...,60
    const int xwr = stg_addr(xm, xk0);    // 4-half aligned
    const float* xrow = x + (size_t)(b0 + xm) * TSEQ * DIN + xk0;

    // ---- prologue: zero h(0); stage x(0); prime accA; leave xbuf[0]=x(1)
    *(half8v*)&hbuf[0][tid << 3] = (half8v)0;
    {
        f32x4 x0 = *(const f32x4*)xrow;
        half4v w; w[0] = (h16)x0[0]; w[1] = (h16)x0[1]; w[2] = (h16)x0[2]; w[3] = (h16)x0[3];
        *(half4v*)&xbuf[0][xwr] = w;
    }
    __syncthreads();

    f32x4 accA[4][2], accB[4][2];
    {
        half8v xf0 = *(const half8v*)&xbuf[0][xa0];
        half8v xf1 = *(const half8v*)&xbuf[0][xa1];
        #pragma unroll
        for (int G = 0; G < 4; ++G)
            #pragma unroll
            for (int nt = 0; nt < 2; ++nt) {
                accA[G][nt] = MFMA16(xf0, bx[G][0][nt], bias_c[G][nt]);
                accA[G][nt] = MFMA16(xf1, bx[G][1][nt], accA[G][nt]);
            }
    }
    __syncthreads();   // protect xbuf[0] overwrite below

    f32x4 xhold, xnew;
    {
        f32x4 x1 = *(const f32x4*)(xrow + DIN);      // x(1)
        half4v w; w[0] = (h16)x1[0]; w[1] = (h16)x1[1]; w[2] = (h16)x1[2]; w[3] = (h16)x1[3];
        *(half4v*)&xbuf[0][xwr] = w;
        xhold = *(const f32x4*)(xrow + 2 * DIN);     // x(2)
        xnew  = *(const f32x4*)(xrow + 3 * DIN);     // x(3)
    }
    __syncthreads();   // x(1) visible before STEP(0)'s pre-barrier read

    f32x4 cstate[2] = {{0.f,0.f,0.f,0.f},{0.f,0.f,0.f,0.f}};

#define STEP(p_, tcur, ACCC, ACCN)                                              \
  {                                                                             \
    /* ===== x-phase (pre-barrier): independent of h(t) ===== */                \
    half8v xf0 = *(const half8v*)&xbuf[p_][xa0];    /* x(tcur+1) */             \
    half8v xf1 = *(const half8v*)&xbuf[p_][xa1];                                \
    { half4v w; w[0] = (h16)xhold[0]; w[1] = (h16)xhold[1];                     \
      w[2] = (h16)xhold[2]; w[3] = (h16)xhold[3];                               \
      *(half4v*)&xbuf[p_ ^ 1][xwr] = w; }          /* stage x(tcur+2) */        \
    xhold = xnew;                                                               \
    const int tpre = ((tcur) + 4 < TSEQ) ? (tcur) + 4 : TSEQ - 1;               \
    xnew = *(const f32x4*)(xrow + (size_t)tpre * DIN);                          \
    _Pragma("unroll")                                                           \
    for (int G = 0; G < 4; ++G)                                                 \
        _Pragma("unroll")                                                       \
        for (int nt = 0; nt < 2; ++nt) {                                        \
            ACCN[G][nt] = MFMA16(xf0, bx[G][0][nt], bias_c[G][nt]);             \
            ACCN[G][nt] = MFMA16(xf1, bx[G][1][nt], ACCN[G][nt]);               \
        }                                                                       \
    __syncthreads();                                                            \
    /* ===== h-phase ===== */                                                   \
    half8v ah0 = *(const half8v*)&hbuf[p_][ha0];                                \
    half8v ah1 = *(const half8v*)&hbuf[p_][ha1];                                \
    half8v ah2 = *(const half8v*)&hbuf[p_][ha2];                                \
    half8v ah3 = *(const half8v*)&hbuf[p_][ha3];                                \
    /* k-major over g,i,f x ntiles: same-acc dependency distance = 6 */         \
    ACCC[0][0] = MFMA16(ah0, bh[0][0][0], ACCC[0][0]);                          \
    ACCC[0][1] = MFMA16(ah0, bh[0][0][1], ACCC[0][1]);                          \
    ACCC[1][0] = MFMA16(ah0, bh[1][0][0], ACCC[1][0]);                          \
    ACCC[1][1] = MFMA16(ah0, bh[1][0][1], ACCC[1][1]);                          \
    ACCC[2][0] = MFMA16(ah0, bh[2][0][0], ACCC[2][0]);                          \
    ACCC[2][1] = MFMA16(ah0, bh[2][0][1], ACCC[2][1]);                          \
    ACCC[0][0] = MFMA16(ah1, bh[0][1][0], ACCC[0][0]);                          \
    ACCC[0][1] = MFMA16(ah1, bh[0][1][1], ACCC[0][1]);                          \
    ACCC[1][0] = MFMA16(ah1, bh[1][1][0], ACCC[1][0]);                          \
    ACCC[1][1] = MFMA16(ah1, bh[1][1][1], ACCC[1][1]);                          \
    ACCC[2][0] = MFMA16(ah1, bh[2][1][0], ACCC[2][0]);                          \
    ACCC[2][1] = MFMA16(ah1, bh[2][1][1], ACCC[2][1]);                          \
    ACCC[0][0] = MFMA16(ah2, bh[0][2][0], ACCC[0][0]);                          \
    ACCC[0][1] = MFMA16(ah2, bh[0][2][1], ACCC[0][1]);                          \
    ACCC[1][0] = MFMA16(ah2, bh[1][2][0], ACCC[1][0]);                          \
    ACCC[1][1] = MFMA16(ah2, bh[1][2][1], ACCC[1][1]);                          \
    ACCC[2][0] = MFMA16(ah2, bh[2][2][0], ACCC[2][0]);                          \
    ACCC[2][1] = MFMA16(ah2, bh[2][2][1], ACCC[2][1]);                          \
    ACCC[0][0] = MFMA16(ah3, bh[0][3][0], ACCC[0][0]);                          \
    ACCC[0][1] = MFMA16(ah3, bh[0][3][1], ACCC[0][1]);                          \
    ACCC[1][0] = MFMA16(ah3, bh[1][3][0], ACCC[1][0]);                          \
    ACCC[1][1] = MFMA16(ah3, bh[1][3][1], ACCC[1][1]);                          \
    ACCC[2][0] = MFMA16(ah3, bh[2][3][0], ACCC[2][0]);                          \
    ACCC[2][1] = MFMA16(ah3, bh[2][3][1], ACCC[2][1]);                          \
    /* o-chains: drain under the c-math below */                                \
    ACCC[3][0] = MFMA16(ah0, bh[3][0][0], ACCC[3][0]);                          \
    ACCC[3][1] = MFMA16(ah0, bh[3][0][1], ACCC[3][1]);                          \
    ACCC[3][0] = MFMA16(ah1, bh[3][1][0], ACCC[3][0]);                          \
    ACCC[3][1] = MFMA16(ah1, bh[3][1][1], ACCC[3][1]);                          \
    ACCC[3][0] = MFMA16(ah2, bh[3][2][0], ACCC[3][0]);                          \
    ACCC[3][1] = MFMA16(ah2, bh[3][2][1], ACCC[3][1]);                          \
    ACCC[3][0] = MFMA16(ah3, bh[3][3][0], ACCC[3][0]);                          \
    ACCC[3][1] = MFMA16(ah3, bh[3][3][1], ACCC[3][1]);                          \
    /* fused c update: 3 exp2 + 1 rcp per element (8 elems, ILP 8) */           \
    f32x4 ycv[2];                                                               \
    _Pragma("unroll")                                                           \
    for (int nt = 0; nt < 2; ++nt)                                              \
        _Pragma("unroll")                                                       \
        for (int r = 0; r < 4; ++r) {                                           \
            float eg = __builtin_amdgcn_exp2f(ACCC[0][nt][r]);                  \
            float ei = __builtin_amdgcn_exp2f(ACCC[1][nt][r]);                  \
            float ef = __builtin_amdgcn_exp2f(ACCC[2][nt][r]);                  \
            float ag = 1.f + eg;                                                \
            float ai = 1.f + ei;                                                \
            float af = 1.f + ef;                                                \
            float dp  = ag * ai;                                                \
            float num = __builtin_fmaf(cstate[nt][r], dp, (1.f - eg) * af);     \
            float c   = num * __builtin_amdgcn_rcpf(dp * af);                   \
            cstate[nt][r] = c;                                                  \
            ycv[nt][r] = fminf(c * SCALE_G, 126.f);                             \
        }                                                                       \
    /* fused h = tanh(c)*sigma(o): 2 exp2 + 1 rcp per element */                \
    h16* hw = hbuf[p_ ^ 1];                                                     \
    _Pragma("unroll")                                                           \
    for (int nt = 0; nt < 2; ++nt)                                              \
        _Pragma("unroll")                                                       \
        for (int r = 0; r < 4; ++r) {                                           \
            float ec = __builtin_amdgcn_exp2f(ycv[nt][r]);                      \
            float eo = __builtin_amdgcn_exp2f(ACCC[3][nt][r]);                  \
            float dh = (1.f + ec) * (1.f + eo);                                 \
            float hv = (1.f - ec) * __builtin_amdgcn_rcpf(dh);                  \
            hw[hwr[nt][r]] = (h16)hv;                                           \
        }                                                                       \
  }

    for (int t = 0; t < TSEQ; t += 2) {
        STEP(0, t,     accA, accB)
        STEP(1, t + 1, accB, accA)
    }
#undef STEP

    __syncthreads();
    // final h is in hbuf[0] (t=511 writes p^1 = 0)
    if (tid < BM * NCLS) {
        const int m = tid / NCLS;
        const int cls = tid - m * NCLS;
        float s = bp[cls];
        #pragma unroll 8
        for (int k = 0; k < H; ++k) {
            float hvv = (float)hbuf[0][stg_addr(m, k)];
            s += hvv * Wph[k * NCLS + cls];
        }
        out[(size_t)(b0 + m) * NCLS + cls] = s;
    }
}

extern "C" void kernel_launch(void* const* d_in, const int* in_sizes, int n_in,
                              void* d_out, int out_size, void* d_ws, size_t ws_size,
                              hipStream_t stream) {
    (void)in_sizes; (void)n_in; (void)d_ws; (void)ws_size; (void)out_size;
    lstm_persist<<<dim3(BATCH / BM), dim3(NTHREADS), 0, stream>>>(
        (const float*)d_in[0],
        (const float*)d_in[1], (const float*)d_in[2],
        (const float*)d_in[3], (const float*)d_in[4],
        (const float*)d_in[5], (const float*)d_in[6],
        (const float*)d_in[7], (const float*)d_in[8],
        (const float*)d_in[9],
        (const float*)d_in[10], (const float*)d_in[11],
        (const float*)d_in[12], (const float*)d_in[13],
        (const float*)d_in[14],
        (float*)d_out);
}

// Round 10
// 418.390 us; speedup vs baseline: 1.2329x; 1.2329x over previous
//
#include <hip/hip_runtime.h>

#define BATCH 1024
#define TSEQ  512
#define DIN   64
#define H     128
#define NCLS  10
#define BM    16
#define NTHREADS 512

typedef _Float16 h16;
typedef __attribute__((ext_vector_type(2))) _Float16 half2v;
typedef __attribute__((ext_vector_type(4))) _Float16 half4v;
typedef __attribute__((ext_vector_type(8))) _Float16 half8v;
typedef __attribute__((ext_vector_type(2))) float f32x2;
typedef __attribute__((ext_vector_type(4))) float f32x4;

// Swizzled staging layout (units: halfs) for a 16-row x K-col fp16 tile.
// chunk(m, kg) = kg*16 + (m ^ (kg&7)); element (m,k) at chunk*8 + (k&7).
// A-frag read: lane(ln,grp) reads chunk(ln, 4s+grp) as one aligned b128;
// 64 distinct chunks per instr -> conflict-free. Writes spread by XOR.
__device__ __forceinline__ int stg_addr(int m, int k) {
    const int kg = k >> 3;
    return (((kg << 4) + (m ^ (kg & 7))) << 3) + (k & 7);
}

#define SCALE_G (-2.8853900817779268f)   /* -2*log2(e): tanh gates */
#define SCALE_S (-1.4426950408889634f)   /* -log2(e):   sigmoid gates */

#define MFMA16(A, B, C) __builtin_amdgcn_mfma_f32_16x16x32_f16((A), (B), (C), 0, 0, 0)

// Persistent LSTM: 64 blocks x 16 batch rows, 8 waves/block (2/SIMD).
// Wave w owns gate columns [16w,16w+16) of all 4 gates -> c/h update is
// register-local. Weights in registers as scale-folded fp16 B-fragments.
// Parity-skewed schedule: the two waves sharing a SIMD place their 8
// x-GEMM MFMAs at opposite ends of the step (odd: pre-barrier; even:
// after gate-VALU), staggering matrix-pipe vs VALU-pipe usage so one
// wave's MFMAs drain under the other's nonlinearities. s_setprio(1)
// around the h-MFMA cluster reinforces the role split.
// Gate math fused over common denominators (7 trans/element):
//   c' = [c*(1+e_g)(1+e_i) + (1-e_g)(1+e_f)] / [(1+e_g)(1+e_i)(1+e_f)]
//   h  = (1-e_c) / ((1+e_c)(1+e_o)),  e_c = exp2(min(c'*SCALE_G, 126))
__global__ __launch_bounds__(NTHREADS, 2)
void lstm_persist(const float* __restrict__ x,
                  const float* __restrict__ Wgx, const float* __restrict__ Wgh,
                  const float* __restrict__ Wix, const float* __restrict__ Wih,
                  const float* __restrict__ Wfx, const float* __restrict__ Wfh,
                  const float* __restrict__ Wox, const float* __restrict__ Woh,
                  const float* __restrict__ Wph,
                  const float* __restrict__ bg, const float* __restrict__ bi,
                  const float* __restrict__ bfg, const float* __restrict__ bo,
                  const float* __restrict__ bp,
                  float* __restrict__ out)
{
    __shared__ __align__(16) h16 hbuf[2][H * BM];    // 2 x 4KB
    __shared__ __align__(16) h16 xbuf[2][DIN * BM];  // 2 x 2KB

    const int tid  = threadIdx.x;
    const int wave = tid >> 6;
    const int lane = tid & 63;
    const int grp  = lane >> 4;
    const int ln   = lane & 15;
    const int b0   = blockIdx.x * BM;
    const int n    = (wave << 4) + ln;   // gate column 0..127
    const bool wodd = (wave & 1);        // per-SIMD wave parity (waves w, w+1 share a SIMD pair-wise)

    // ---- weights -> register B-fragments (fp32 -> fp16, scale folded)
    half8v bx[4][2];
    half8v bh[4][4];
    f32x4  bias_c[4];
    {
        const float* WX[4] = {Wgx, Wix, Wfx, Wox};
        const float* WH[4] = {Wgh, Wih, Wfh, Woh};
        const float* BB[4] = {bg, bi, bfg, bo};
        const float  SC[4] = {SCALE_G, SCALE_S, SCALE_S, SCALE_S};
        #pragma unroll
        for (int G = 0; G < 4; ++G) {
            #pragma unroll
            for (int s = 0; s < 2; ++s) {
                half8v v;
                #pragma unroll
                for (int j = 0; j < 8; ++j)
                    v[j] = (h16)(WX[G][(32*s + 8*grp + j) * H + n] * SC[G]);
                bx[G][s] = v;
            }
            #pragma unroll
            for (int s = 0; s < 4; ++s) {
                half8v v;
                #pragma unroll
                for (int j = 0; j < 8; ++j)
                    v[j] = (h16)(WH[G][(32*s + 8*grp + j) * H + n] * SC[G]);
                bh[G][s] = v;
            }
            const float bb = BB[G][n] * SC[G];
            bias_c[G] = (f32x4){bb, bb, bb, bb};
        }
    }

    // ---- hoisted LDS addresses
    const int ha0 = stg_addr(ln,      8 * grp);
    const int ha1 = stg_addr(ln, 32 + 8 * grp);
    const int ha2 = stg_addr(ln, 64 + 8 * grp);
    const int ha3 = stg_addr(ln, 96 + 8 * grp);
    const int xa0 = ha0;                       // xbuf uses same 16x64 layout
    const int xa1 = ha1;
    int hwr[4];
    #pragma unroll
    for (int r = 0; r < 4; ++r) hwr[r] = stg_addr((grp << 2) + r, n);

    // ---- x stager: ALL 512 threads, 2 floats (8B) each
    const int xm  = tid >> 5;             // row 0..15
    const int xk0 = (tid & 31) << 1;      // k 0,2,...,62
    const int xwr = stg_addr(xm, xk0);    // b32-aligned (xk0 even)
    const float* xrow = x + (size_t)(b0 + xm) * TSEQ * DIN + xk0;

    // ---- prologue: zero h(0); prime accA with bias + x(0)-part;
    //      leave xbuf[0]=x(1), xhold=x(2), xnew=x(3).
    *(half4v*)&hbuf[0][tid << 2] = (half4v)0;
    {
        f32x2 x0 = *(const f32x2*)xrow;
        half2v w; w[0] = (h16)x0[0]; w[1] = (h16)x0[1];
        *(half2v*)&xbuf[0][xwr] = w;
    }
    __syncthreads();

    f32x4 accA[4], accB[4];
    {
        half8v xf0 = *(const half8v*)&xbuf[0][xa0];
        half8v xf1 = *(const half8v*)&xbuf[0][xa1];
        #pragma unroll
        for (int G = 0; G < 4; ++G) {
            accA[G] = MFMA16(xf0, bx[G][0], bias_c[G]);
            accA[G] = MFMA16(xf1, bx[G][1], accA[G]);
        }
    }
    __syncthreads();   // protect xbuf[0] overwrite below

    f32x2 xhold, xnew;
    {
        f32x2 x1 = *(const f32x2*)(xrow + DIN);      // x(1)
        half2v w; w[0] = (h16)x1[0]; w[1] = (h16)x1[1];
        *(half2v*)&xbuf[0][xwr] = w;
        xhold = *(const f32x2*)(xrow + 2 * DIN);     // x(2)
        xnew  = *(const f32x2*)(xrow + 3 * DIN);     // x(3)
    }
    __syncthreads();   // x(1) visible before STEP(0)'s pre-barrier read

    f32x4 cstate = {0.f, 0.f, 0.f, 0.f};

#define XGEMM(ACCN)                                                             \
    _Pragma("unroll")                                                           \
    for (int G = 0; G < 4; ++G) {                                               \
        ACCN[G] = MFMA16(xf0, bx[G][0], bias_c[G]);                             \
        ACCN[G] = MFMA16(xf1, bx[G][1], ACCN[G]);                               \
    }

// One LSTM step. ACCC = bias + x(t)-part (primed by the previous step's
// x-GEMM); ACCN receives bias + x(t+1)-part. LDS traffic is identical for
// both parities (all xbuf writes pre-barrier); only MFMA placement skews.
#define STEP(p_, tcur, ACCC, ACCN)                                              \
  {                                                                             \
    /* ===== pre-barrier: x reads/stage (all waves), x-GEMM (odd waves) */      \
    half8v xf0 = *(const half8v*)&xbuf[p_][xa0];    /* x(tcur+1) */             \
    half8v xf1 = *(const half8v*)&xbuf[p_][xa1];                                \
    { half2v w; w[0] = (h16)xhold[0]; w[1] = (h16)xhold[1];                     \
      *(half2v*)&xbuf[p_ ^ 1][xwr] = w; }          /* stage x(tcur+2) */        \
    xhold = xnew;                                                               \
    const int tpre = ((tcur) + 4 < TSEQ) ? (tcur) + 4 : TSEQ - 1;               \
    xnew = *(const f32x2*)(xrow + (size_t)tpre * DIN);                          \
    if (wodd) { XGEMM(ACCN) }                                                   \
    __syncthreads();                                                            \
    /* ===== h-phase ===== */                                                   \
    half8v ah0 = *(const half8v*)&hbuf[p_][ha0];                                \
    half8v ah1 = *(const half8v*)&hbuf[p_][ha1];                                \
    half8v ah2 = *(const half8v*)&hbuf[p_][ha2];                                \
    half8v ah3 = *(const half8v*)&hbuf[p_][ha3];                                \
    __builtin_amdgcn_s_setprio(1);                                              \
    /* k-major over g,i,f: same-acc dependency distance = 3 */                  \
    ACCC[0] = MFMA16(ah0, bh[0][0], ACCC[0]);                                   \
    ACCC[1] = MFMA16(ah0, bh[1][0], ACCC[1]);                                   \
    ACCC[2] = MFMA16(ah0, bh[2][0], ACCC[2]);                                   \
    ACCC[0] = MFMA16(ah1, bh[0][1], ACCC[0]);                                   \
    ACCC[1] = MFMA16(ah1, bh[1][1], ACCC[1]);                                   \
    ACCC[2] = MFMA16(ah1, bh[2][1], ACCC[2]);                                   \
    ACCC[0] = MFMA16(ah2, bh[0][2], ACCC[0]);                                   \
    ACCC[1] = MFMA16(ah2, bh[1][2], ACCC[1]);                                   \
    ACCC[2] = MFMA16(ah2, bh[2][2], ACCC[2]);                                   \
    ACCC[0] = MFMA16(ah3, bh[0][3], ACCC[0]);                                   \
    ACCC[1] = MFMA16(ah3, bh[1][3], ACCC[1]);                                   \
    ACCC[2] = MFMA16(ah3, bh[2][3], ACCC[2]);                                   \
    /* o-chain: drains under the c-math below */                                \
    ACCC[3] = MFMA16(ah0, bh[3][0], ACCC[3]);                                   \
    ACCC[3] = MFMA16(ah1, bh[3][1], ACCC[3]);                                   \
    ACCC[3] = MFMA16(ah2, bh[3][2], ACCC[3]);                                   \
    ACCC[3] = MFMA16(ah3, bh[3][3], ACCC[3]);                                   \
    __builtin_amdgcn_s_setprio(0);                                              \
    /* fused c update: 3 exp2 + 1 rcp per element */                            \
    f32x4 ycv;                                                                  \
    _Pragma("unroll")                                                           \
    for (int r = 0; r < 4; ++r) {                                               \
        float eg = __builtin_amdgcn_exp2f(ACCC[0][r]);                          \
        float ei = __builtin_amdgcn_exp2f(ACCC[1][r]);                          \
        float ef = __builtin_amdgcn_exp2f(ACCC[2][r]);                          \
        float ag = 1.f + eg;                                                    \
        float ai = 1.f + ei;                                                    \
        float af = 1.f + ef;                                                    \
        float dp  = ag * ai;                                                    \
        float num = __builtin_fmaf(cstate[r], dp, (1.f - eg) * af);             \
        float c   = num * __builtin_amdgcn_rcpf(dp * af);                       \
        cstate[r] = c;                                                          \
        ycv[r] = fminf(c * SCALE_G, 126.f);                                     \
    }                                                                           \
    /* fused h = tanh(c)*sigma(o): 2 exp2 + 1 rcp per element */                \
    h16* hw = hbuf[p_ ^ 1];                                                     \
    _Pragma("unroll")                                                           \
    for (int r = 0; r < 4; ++r) {                                               \
        float ec = __builtin_amdgcn_exp2f(ycv[r]);                              \
        float eo = __builtin_amdgcn_exp2f(ACCC[3][r]);                          \
        float dh = (1.f + ec) * (1.f + eo);                                     \
        float hv = (1.f - ec) * __builtin_amdgcn_rcpf(dh);                      \
        hw[hwr[r]] = (h16)hv;                                                   \
    }                                                                           \
    /* even waves: x-GEMM last -> drains under the odd wave's VALU */           \
    if (!wodd) { XGEMM(ACCN) }                                                  \
  }

    for (int t = 0; t < TSEQ; t += 2) {
        STEP(0, t,     accA, accB)
        STEP(1, t + 1, accB, accA)
    }
#undef STEP
#undef XGEMM

    __syncthreads();
    // final h is in hbuf[0] (t=511 writes p^1 = 0)
    if (tid < BM * NCLS) {
        const int m = tid / NCLS;
        const int cls = tid - m * NCLS;
        float s = bp[cls];
        #pragma unroll 8
        for (int k = 0; k < H; ++k) {
            float hvv = (float)hbuf[0][stg_addr(m, k)];
            s += hvv * Wph[k * NCLS + cls];
        }
        out[(size_t)(b0 + m) * NCLS + cls] = s;
    }
}

extern "C" void kernel_launch(void* const* d_in, const int* in_sizes, int n_in,
                              void* d_out, int out_size, void* d_ws, size_t ws_size,
                              hipStream_t stream) {
    (void)in_sizes; (void)n_in; (void)d_ws; (void)ws_size; (void)out_size;
    lstm_persist<<<dim3(BATCH / BM), dim3(NTHREADS), 0, stream>>>(
        (const float*)d_in[0],
        (const float*)d_in[1], (const float*)d_in[2],
        (const float*)d_in[3], (const float*)d_in[4],
        (const float*)d_in[5], (const float*)d_in[6],
        (const float*)d_in[7], (const float*)d_in[8],
        (const float*)d_in[9],
        (const float*)d_in[10], (const float*)d_in[11],
        (const float*)d_in[12], (const float*)d_in[13],
        (const float*)d_in[14],
        (float*)d_out);
}

// Round 11
// 380.508 us; speedup vs baseline: 1.3556x; 1.0996x over previous
//
#include <hip/hip_runtime.h>

#define BATCH 1024
#define TSEQ  512
#define DIN   64
#define H     128
#define NCLS  10
#define BM    16
#define NTHREADS 512

typedef _Float16 h16;
typedef __attribute__((ext_vector_type(2))) _Float16 half2v;
typedef __attribute__((ext_vector_type(4))) _Float16 half4v;
typedef __attribute__((ext_vector_type(8))) _Float16 half8v;
typedef __attribute__((ext_vector_type(2))) float f32x2;
typedef __attribute__((ext_vector_type(4))) float f32x4;

// Swizzled staging layout (units: halfs) for a 16-row x K-col fp16 tile.
// chunk(m, kg) = kg*16 + (m ^ (kg&7)); element (m,k) at chunk*8 + (k&7).
// A-frag read: lane(ln,grp) reads chunk(ln, 4s+grp) as one aligned b128;
// 64 distinct chunks per instr -> conflict-free. Writes spread by XOR.
__device__ __forceinline__ int stg_addr(int m, int k) {
    const int kg = k >> 3;
    return (((kg << 4) + (m ^ (kg & 7))) << 3) + (k & 7);
}

#define SCALE_G (-2.8853900817779268f)   /* -2*log2(e): tanh gates */
#define SCALE_S (-1.4426950408889634f)   /* -log2(e):   sigmoid gates */

#define MFMA16(A, B, C) __builtin_amdgcn_mfma_f32_16x16x32_f16((A), (B), (C), 0, 0, 0)
#define EXP2(v) __builtin_amdgcn_exp2f(v)
#define RCP(v)  __builtin_amdgcn_rcpf(v)

// Fused c update over a 2-element pair (packed f32x2 -> v_pk_* ops):
//   c' = [c*(1+e_g)(1+e_i) + (1-e_g)(1+e_f)] / [(1+e_g)(1+e_i)(1+e_f)]
#define CMATH(ACC, PAIR, CST, YCV)                                              \
  {                                                                             \
    f32x2 eg = { EXP2(ACC[0][2*(PAIR)]), EXP2(ACC[0][2*(PAIR)+1]) };            \
    f32x2 ei = { EXP2(ACC[1][2*(PAIR)]), EXP2(ACC[1][2*(PAIR)+1]) };            \
    f32x2 ef = { EXP2(ACC[2][2*(PAIR)]), EXP2(ACC[2][2*(PAIR)+1]) };            \
    f32x2 ag = one2 + eg, ai = one2 + ei, af = one2 + ef;                       \
    f32x2 dp  = ag * ai;                                                        \
    f32x2 t1  = (one2 - eg) * af;                                               \
    f32x2 num = CST * dp + t1;                                                  \
    f32x2 den = dp * af;                                                        \
    f32x2 rd  = { RCP(den[0]), RCP(den[1]) };                                   \
    f32x2 c   = num * rd;                                                       \
    CST = c;                                                                    \
    f32x2 yc = c * sg2;                                                         \
    YCV[0] = fminf(yc[0], 126.f);                                               \
    YCV[1] = fminf(yc[1], 126.f);                                               \
  }

// Fused h = tanh(c)*sigma(o) for a pair, with immediate LDS write
//   h = (1-e_c) / ((1+e_c)(1+e_o))
#define HMATH(ACC, PAIR, YCV)                                                   \
  {                                                                             \
    f32x2 ec = { EXP2(YCV[0]), EXP2(YCV[1]) };                                  \
    f32x2 eo = { EXP2(ACC[3][2*(PAIR)]), EXP2(ACC[3][2*(PAIR)+1]) };            \
    f32x2 dh = (one2 + ec) * (one2 + eo);                                       \
    f32x2 nh = one2 - ec;                                                       \
    f32x2 rh = { RCP(dh[0]), RCP(dh[1]) };                                      \
    f32x2 hv = nh * rh;                                                         \
    hw[hwr[2*(PAIR)]]     = (h16)hv[0];                                         \
    hw[hwr[2*(PAIR) + 1]] = (h16)hv[1];                                         \
  }

// Persistent LSTM: 64 blocks x 16 batch rows, 8 waves/block (2/SIMD).
// Wave w owns gate columns [16w,16w+16) of all 4 gates -> c/h update is
// register-local. Weights in registers as scale-folded fp16 B-fragments.
// Schedule per step: pre-barrier x-pipeline (stage + x-GEMM(t+1) into the
// spare acc buffer, drains under barrier-wait + ds_read); post-barrier
// k-major g/i/f chains, o-chain, packed c-math (overlaps o drain), packed
// h-math + immediate writes.
__global__ __launch_bounds__(NTHREADS, 2)
void lstm_persist(const float* __restrict__ x,
                  const float* __restrict__ Wgx, const float* __restrict__ Wgh,
                  const float* __restrict__ Wix, const float* __restrict__ Wih,
                  const float* __restrict__ Wfx, const float* __restrict__ Wfh,
                  const float* __restrict__ Wox, const float* __restrict__ Woh,
                  const float* __restrict__ Wph,
                  const float* __restrict__ bg, const float* __restrict__ bi,
                  const float* __restrict__ bfg, const float* __restrict__ bo,
                  const float* __restrict__ bp,
                  float* __restrict__ out)
{
    __shared__ __align__(16) h16 hbuf[2][H * BM];    // 2 x 4KB
    __shared__ __align__(16) h16 xbuf[2][DIN * BM];  // 2 x 2KB

    const int tid  = threadIdx.x;
    const int wave = tid >> 6;
    const int lane = tid & 63;
    const int grp  = lane >> 4;
    const int ln   = lane & 15;
    const int b0   = blockIdx.x * BM;
    const int n    = (wave << 4) + ln;   // gate column 0..127

    // ---- weights -> register B-fragments (fp32 -> fp16, scale folded)
    half8v bx[4][2];
    half8v bh[4][4];
    f32x4  bias_c[4];
    {
        const float* WX[4] = {Wgx, Wix, Wfx, Wox};
        const float* WH[4] = {Wgh, Wih, Wfh, Woh};
        const float* BB[4] = {bg, bi, bfg, bo};
        const float  SC[4] = {SCALE_G, SCALE_S, SCALE_S, SCALE_S};
        #pragma unroll
        for (int G = 0; G < 4; ++G) {
            #pragma unroll
            for (int s = 0; s < 2; ++s) {
                half8v v;
                #pragma unroll
                for (int j = 0; j < 8; ++j)
                    v[j] = (h16)(WX[G][(32*s + 8*grp + j) * H + n] * SC[G]);
                bx[G][s] = v;
            }
            #pragma unroll
            for (int s = 0; s < 4; ++s) {
                half8v v;
                #pragma unroll
                for (int j = 0; j < 8; ++j)
                    v[j] = (h16)(WH[G][(32*s + 8*grp + j) * H + n] * SC[G]);
                bh[G][s] = v;
            }
            const float bb = BB[G][n] * SC[G];
            bias_c[G] = (f32x4){bb, bb, bb, bb};
        }
    }

    // ---- hoisted LDS addresses
    const int ha0 = stg_addr(ln,      8 * grp);
    const int ha1 = stg_addr(ln, 32 + 8 * grp);
    const int ha2 = stg_addr(ln, 64 + 8 * grp);
    const int ha3 = stg_addr(ln, 96 + 8 * grp);
    const int xa0 = ha0;                       // xbuf uses same 16x64 layout
    const int xa1 = ha1;
    int hwr[4];
    #pragma unroll
    for (int r = 0; r < 4; ++r) hwr[r] = stg_addr((grp << 2) + r, n);

    // ---- x stager: ALL 512 threads, 2 floats (8B) each
    const int xm  = tid >> 5;             // row 0..15
    const int xk0 = (tid & 31) << 1;      // k 0,2,...,62
    const int xwr = stg_addr(xm, xk0);    // b32-aligned (xk0 even)
    const float* xrow = x + (size_t)(b0 + xm) * TSEQ * DIN + xk0;

    const f32x2 one2 = {1.f, 1.f};
    const f32x2 sg2  = {SCALE_G, SCALE_G};

    // ---- prologue: zero h(0); prime accA with bias + x(0)-part;
    //      leave xbuf[0]=x(1), xhold=x(2), xnew=x(3).
    *(half4v*)&hbuf[0][tid << 2] = (half4v)0;
    {
        f32x2 x0 = *(const f32x2*)xrow;
        *(half2v*)&xbuf[0][xwr] =
            __builtin_bit_cast(half2v, __builtin_amdgcn_cvt_pkrtz(x0[0], x0[1]));
    }
    __syncthreads();

    f32x4 accA[4], accB[4];
    {
        half8v xf0 = *(const half8v*)&xbuf[0][xa0];
        half8v xf1 = *(const half8v*)&xbuf[0][xa1];
        #pragma unroll
        for (int G = 0; G < 4; ++G) {
            accA[G] = MFMA16(xf0, bx[G][0], bias_c[G]);
            accA[G] = MFMA16(xf1, bx[G][1], accA[G]);
        }
    }
    __syncthreads();   // protect xbuf[0] overwrite below

    f32x2 xhold, xnew;
    {
        f32x2 x1 = *(const f32x2*)(xrow + DIN);      // x(1)
        *(half2v*)&xbuf[0][xwr] =
            __builtin_bit_cast(half2v, __builtin_amdgcn_cvt_pkrtz(x1[0], x1[1]));
        xhold = *(const f32x2*)(xrow + 2 * DIN);     // x(2)
        xnew  = *(const f32x2*)(xrow + 3 * DIN);     // x(3)
    }
    __syncthreads();   // x(1) visible before STEP(0)'s pre-barrier read

    f32x2 cst01 = {0.f, 0.f};
    f32x2 cst23 = {0.f, 0.f};

// One LSTM step. ACCC = bias + x(t)-part (primed by the previous step's
// pre-barrier x-GEMM); ACCN receives bias + x(t+1)-part.
#define STEP(p_, tcur, ACCC, ACCN)                                              \
  {                                                                             \
    /* ===== x-phase (pre-barrier): independent of h(t) ===== */                \
    half8v xf0 = *(const half8v*)&xbuf[p_][xa0];    /* x(tcur+1) */             \
    half8v xf1 = *(const half8v*)&xbuf[p_][xa1];                                \
    *(half2v*)&xbuf[p_ ^ 1][xwr] =                                              \
        __builtin_bit_cast(half2v, __builtin_amdgcn_cvt_pkrtz(xhold[0], xhold[1])); \
    xhold = xnew;                                                               \
    const int tpre = ((tcur) + 4 < TSEQ) ? (tcur) + 4 : TSEQ - 1;               \
    xnew = *(const f32x2*)(xrow + (size_t)tpre * DIN);                          \
    _Pragma("unroll")                                                           \
    for (int G = 0; G < 4; ++G) {                                               \
        ACCN[G] = MFMA16(xf0, bx[G][0], bias_c[G]);                             \
        ACCN[G] = MFMA16(xf1, bx[G][1], ACCN[G]);                               \
    }                                                                           \
    __syncthreads();                                                            \
    /* ===== h-phase ===== */                                                   \
    half8v ah0 = *(const half8v*)&hbuf[p_][ha0];                                \
    half8v ah1 = *(const half8v*)&hbuf[p_][ha1];                                \
    half8v ah2 = *(const half8v*)&hbuf[p_][ha2];                                \
    half8v ah3 = *(const half8v*)&hbuf[p_][ha3];                                \
    /* k-major over g,i,f: same-acc dependency distance = 3 */                  \
    ACCC[0] = MFMA16(ah0, bh[0][0], ACCC[0]);                                   \
    ACCC[1] = MFMA16(ah0, bh[1][0], ACCC[1]);                                   \
    ACCC[2] = MFMA16(ah0, bh[2][0], ACCC[2]);                                   \
    ACCC[0] = MFMA16(ah1, bh[0][1], ACCC[0]);                                   \
    ACCC[1] = MFMA16(ah1, bh[1][1], ACCC[1]);                                   \
    ACCC[2] = MFMA16(ah1, bh[2][1], ACCC[2]);                                   \
    ACCC[0] = MFMA16(ah2, bh[0][2], ACCC[0]);                                   \
    ACCC[1] = MFMA16(ah2, bh[1][2], ACCC[1]);                                   \
    ACCC[2] = MFMA16(ah2, bh[2][2], ACCC[2]);                                   \
    ACCC[0] = MFMA16(ah3, bh[0][3], ACCC[0]);                                   \
    ACCC[1] = MFMA16(ah3, bh[1][3], ACCC[1]);                                   \
    ACCC[2] = MFMA16(ah3, bh[2][3], ACCC[2]);                                   \
    /* o-chain: drains under the packed c-math below */                         \
    ACCC[3] = MFMA16(ah0, bh[3][0], ACCC[3]);                                   \
    ACCC[3] = MFMA16(ah1, bh[3][1], ACCC[3]);                                   \
    ACCC[3] = MFMA16(ah2, bh[3][2], ACCC[3]);                                   \
    ACCC[3] = MFMA16(ah3, bh[3][3], ACCC[3]);                                   \
    f32x2 yc0, yc1;                                                             \
    CMATH(ACCC, 0, cst01, yc0)                                                  \
    CMATH(ACCC, 1, cst23, yc1)                                                  \
    h16* hw = hbuf[p_ ^ 1];                                                     \
    HMATH(ACCC, 0, yc0)                                                         \
    HMATH(ACCC, 1, yc1)                                                         \
  }

    for (int t = 0; t < TSEQ; t += 2) {
        STEP(0, t,     accA, accB)
        STEP(1, t + 1, accB, accA)
    }
#undef STEP

    __syncthreads();
    // final h is in hbuf[0] (t=511 writes p^1 = 0)
    if (tid < BM * NCLS) {
        const int m = tid / NCLS;
        const int cls = tid - m * NCLS;
        float s = bp[cls];
        #pragma unroll 8
        for (int k = 0; k < H; ++k) {
            float hvv = (float)hbuf[0][stg_addr(m, k)];
            s += hvv * Wph[k * NCLS + cls];
        }
        out[(size_t)(b0 + m) * NCLS + cls] = s;
    }
}

extern "C" void kernel_launch(void* const* d_in, const int* in_sizes, int n_in,
                              void* d_out, int out_size, void* d_ws, size_t ws_size,
                              hipStream_t stream) {
    (void)in_sizes; (void)n_in; (void)d_ws; (void)ws_size; (void)out_size;
    lstm_persist<<<dim3(BATCH / BM), dim3(NTHREADS), 0, stream>>>(
        (const float*)d_in[0],
        (const float*)d_in[1], (const float*)d_in[2],
        (const float*)d_in[3], (const float*)d_in[4],
        (const float*)d_in[5], (const float*)d_in[6],
        (const float*)d_in[7], (const float*)d_in[8],
        (const float*)d_in[9],
        (const float*)d_in[10], (const float*)d_in[11],
        (const float*)d_in[12], (const float*)d_in[13],
        (const float*)d_in[14],
        (float*)d_out);
}

// Round 12
// 378.576 us; speedup vs baseline: 1.3625x; 1.0051x over previous
//
#include <hip/hip_runtime.h>

#define BATCH 1024
#define TSEQ  512
#define DIN   64
#define H     128
#define NCLS  10
#define BM    16
#define NTHREADS 512
#define NCONS 64
#define NPROD 192
#define TSTRIDE ((size_t)64 * 8192)   /* halfs per t-slice of preact buffer */

typedef _Float16 h16;
typedef __attribute__((ext_vector_type(2))) _Float16 half2v;
typedef __attribute__((ext_vector_type(4))) _Float16 half4v;
typedef __attribute__((ext_vector_type(8))) _Float16 half8v;
typedef __attribute__((ext_vector_type(2))) float f32x2;
typedef __attribute__((ext_vector_type(4))) float f32x4;

// Swizzled staging layout (units: halfs) for a 16-row x K-col fp16 tile.
// chunk(m, kg) = kg*16 + (m ^ (kg&7)); element (m,k) at chunk*8 + (k&7).
__device__ __forceinline__ int stg_addr(int m, int k) {
    const int kg = k >> 3;
    return (((kg << 4) + (m ^ (kg & 7))) << 3) + (k & 7);
}

#define SCALE_G (-2.8853900817779268f)   /* -2*log2(e): tanh gates */
#define SCALE_S (-1.4426950408889634f)   /* -log2(e):   sigmoid gates */

#define MFMA16(A, B, C) __builtin_amdgcn_mfma_f32_16x16x32_f16((A), (B), (C), 0, 0, 0)
#define EXP2(v) __builtin_amdgcn_exp2f(v)
#define RCP(v)  __builtin_amdgcn_rcpf(v)

// Fused c update over a 2-element pair (packed f32x2):
//   c' = [c*(1+e_g)(1+e_i) + (1-e_g)(1+e_f)] / [(1+e_g)(1+e_i)(1+e_f)]
#define CMATH(ACC, PAIR, CST, YCV)                                              \
  {                                                                             \
    f32x2 eg = { EXP2(ACC[0][2*(PAIR)]), EXP2(ACC[0][2*(PAIR)+1]) };            \
    f32x2 ei = { EXP2(ACC[1][2*(PAIR)]), EXP2(ACC[1][2*(PAIR)+1]) };            \
    f32x2 ef = { EXP2(ACC[2][2*(PAIR)]), EXP2(ACC[2][2*(PAIR)+1]) };            \
    f32x2 ag = one2 + eg, ai = one2 + ei, af = one2 + ef;                       \
    f32x2 dp  = ag * ai;                                                        \
    f32x2 t1  = (one2 - eg) * af;                                               \
    f32x2 num = CST * dp + t1;                                                  \
    f32x2 den = dp * af;                                                        \
    f32x2 rd  = { RCP(den[0]), RCP(den[1]) };                                   \
    f32x2 c   = num * rd;                                                       \
    CST = c;                                                                    \
    f32x2 yc = c * sg2;                                                         \
    YCV[0] = fminf(yc[0], 126.f);                                               \
    YCV[1] = fminf(yc[1], 126.f);                                               \
  }

// Fused h = tanh(c)*sigma(o):  h = (1-e_c) / ((1+e_c)(1+e_o))
#define HMATH(ACC, PAIR, YCV)                                                   \
  {                                                                             \
    f32x2 ec = { EXP2(YCV[0]), EXP2(YCV[1]) };                                  \
    f32x2 eo = { EXP2(ACC[3][2*(PAIR)]), EXP2(ACC[3][2*(PAIR)+1]) };            \
    f32x2 dh = (one2 + ec) * (one2 + eo);                                       \
    f32x2 nh = one2 - ec;                                                       \
    f32x2 rh = { RCP(dh[0]), RCP(dh[1]) };                                      \
    f32x2 hv = nh * rh;                                                         \
    hw[hwr[2*(PAIR)]]     = (h16)hv[0];                                         \
    hw[hwr[2*(PAIR) + 1]] = (h16)hv[1];                                         \
  }

// unpack 16 preact halfs (2x uint4) into 4 f32x4 accumulators
#define CVTACC(ACC, A0, A1)                                                     \
  {                                                                             \
    half2v u0 = __builtin_bit_cast(half2v, A0.x);                               \
    half2v u1 = __builtin_bit_cast(half2v, A0.y);                               \
    ACC[0] = (f32x4){(float)u0[0], (float)u0[1], (float)u1[0], (float)u1[1]};   \
    half2v u2 = __builtin_bit_cast(half2v, A0.z);                               \
    half2v u3 = __builtin_bit_cast(half2v, A0.w);                               \
    ACC[1] = (f32x4){(float)u2[0], (float)u2[1], (float)u3[0], (float)u3[1]};   \
    half2v u4 = __builtin_bit_cast(half2v, A1.x);                               \
    half2v u5 = __builtin_bit_cast(half2v, A1.y);                               \
    ACC[2] = (f32x4){(float)u4[0], (float)u4[1], (float)u5[0], (float)u5[1]};   \
    half2v u6 = __builtin_bit_cast(half2v, A1.z);                               \
    half2v u7 = __builtin_bit_cast(half2v, A1.w);                               \
    ACC[3] = (f32x4){(float)u6[0], (float)u6[1], (float)u7[0], (float)u7[1]};   \
  }

// ============================================================================
// Fused producer/consumer kernel (grid = 256 blocks):
//   blocks 0..63    : recurrent consumers (1 per 16 batch rows)
//   blocks 64..255  : x-preact producers (3 per batch-block, chunks rr'd)
// Producers compute preact_x = (bias + x W_x) * SC[G] and store in f16 in
// exactly the consumer lane's MFMA D-fragment layout:
//   pre[((t*64 + b)*8 + wave)*64 + lane][16]   (32 B/lane, contiguous)
// Flag per (b, 16-step chunk): release-store after threadfence.
// Consumers: acquire-spin (tid0) every 16 steps; 2-step-deep preact prefetch;
// per step only the h-GEMM (16 MFMA/wave) + fused packed gate math.
// ============================================================================
__global__ __launch_bounds__(NTHREADS, 2)
void lstm_fused(const float* __restrict__ x,
                const float* __restrict__ Wgx, const float* __restrict__ Wgh,
                const float* __restrict__ Wix, const float* __restrict__ Wih,
                const float* __restrict__ Wfx, const float* __restrict__ Wfh,
                const float* __restrict__ Wox, const float* __restrict__ Woh,
                const float* __restrict__ Wph,
                const float* __restrict__ bg, const float* __restrict__ bi,
                const float* __restrict__ bfg, const float* __restrict__ bo,
                const float* __restrict__ bp,
                float* __restrict__ out,
                h16* __restrict__ pre, unsigned* __restrict__ flags)
{
    __shared__ __align__(16) h16 smem[8192];   // 16 KB

    const int tid  = threadIdx.x;
    const int wave = tid >> 6;
    const int lane = tid & 63;
    const int grp  = lane >> 4;
    const int ln   = lane & 15;
    const float SC[4] = {SCALE_G, SCALE_S, SCALE_S, SCALE_S};

    if (blockIdx.x >= NCONS) {
        // ========================= PRODUCER =========================
        const int pb = blockIdx.x - NCONS;   // 0..191
        const int b  = pb & 63;
        const int j  = pb >> 6;              // 0..2: chunk stride-3 offset
        const int n  = (wave << 4) + ln;

        half8v bx[4][2];
        f32x4  bias_c[4];
        {
            const float* WX[4] = {Wgx, Wix, Wfx, Wox};
            const float* BB[4] = {bg, bi, bfg, bo};
            #pragma unroll
            for (int G = 0; G < 4; ++G) {
                #pragma unroll
                for (int s = 0; s < 2; ++s) {
                    half8v v;
                    #pragma unroll
                    for (int q = 0; q < 8; ++q)
                        v[q] = (h16)(WX[G][(32*s + 8*grp + q) * H + n] * SC[G]);
                    bx[G][s] = v;
                }
                const float bb = BB[G][n] * SC[G];
                bias_c[G] = (f32x4){bb, bb, bb, bb};
            }
        }

        // staging: thread stages tile tt=wave, row=sub>>2, k0=(sub&3)*16
        const int sub  = tid & 63;
        const int srow = sub >> 2;
        const int sk0  = (sub & 3) << 4;
        const int swr0 = stg_addr(srow, sk0);
        const int swr1 = stg_addr(srow, sk0 + 8);
        const float* xg0 = x + ((size_t)(b * BM + srow) * TSEQ) * DIN + sk0;
        const int pxa0 = stg_addr(ln,      8 * grp);
        const int pxa1 = stg_addr(ln, 32 + 8 * grp);
        h16* outbase = pre + (size_t)b * 8192 + wave * 1024 + lane * 16;

        for (int c = j; c < 32; c += 3) {
            #pragma unroll
            for (int hf = 0; hf < 2; ++hf) {
                const int t0 = (c << 4) + (hf << 3);
                __syncthreads();   // prior chunk's LDS reads complete
                {
                    const float* xs = xg0 + (size_t)(t0 + wave) * DIN;
                    f32x4 v0 = *(const f32x4*)(xs);
                    f32x4 v1 = *(const f32x4*)(xs + 4);
                    f32x4 v2 = *(const f32x4*)(xs + 8);
                    f32x4 v3 = *(const f32x4*)(xs + 12);
                    half8v h0, h1;
                    #pragma unroll
                    for (int q = 0; q < 4; ++q) {
                        h0[q] = (h16)v0[q]; h0[4+q] = (h16)v1[q];
                        h1[q] = (h16)v2[q]; h1[4+q] = (h16)v3[q];
                    }
                    *(half8v*)&smem[wave * 1024 + swr0] = h0;
                    *(half8v*)&smem[wave * 1024 + swr1] = h1;
                }
                __syncthreads();
                #pragma unroll
                for (int tt = 0; tt < 8; ++tt) {
                    half8v ax0 = *(const half8v*)&smem[tt * 1024 + pxa0];
                    half8v ax1 = *(const half8v*)&smem[tt * 1024 + pxa1];
                    unsigned u[8];
                    #pragma unroll
                    for (int G = 0; G < 4; ++G) {
                        f32x4 a = MFMA16(ax0, bx[G][0], bias_c[G]);
                        a = MFMA16(ax1, bx[G][1], a);
                        u[2*G]   = __builtin_bit_cast(unsigned, __builtin_amdgcn_cvt_pkrtz(a[0], a[1]));
                        u[2*G+1] = __builtin_bit_cast(unsigned, __builtin_amdgcn_cvt_pkrtz(a[2], a[3]));
                    }
                    uint4* dst = (uint4*)(outbase + (size_t)(t0 + tt) * TSTRIDE);
                    dst[0] = make_uint4(u[0], u[1], u[2], u[3]);
                    dst[1] = make_uint4(u[4], u[5], u[6], u[7]);
                }
            }
            __threadfence();      // flush this block's stores device-wide
            __syncthreads();
            if (tid == 0)
                __hip_atomic_store(&flags[b * 32 + c], 1u,
                                   __ATOMIC_RELEASE, __HIP_MEMORY_SCOPE_AGENT);
        }
        return;
    }

    // ========================= CONSUMER =========================
    const int b  = blockIdx.x;
    const int b0 = b * BM;
    const int n  = (wave << 4) + ln;

    half8v bh[4][4];
    {
        const float* WH[4] = {Wgh, Wih, Wfh, Woh};
        #pragma unroll
        for (int G = 0; G < 4; ++G)
            #pragma unroll
            for (int s = 0; s < 4; ++s) {
                half8v v;
                #pragma unroll
                for (int q = 0; q < 8; ++q)
                    v[q] = (h16)(WH[G][(32*s + 8*grp + q) * H + n] * SC[G]);
                bh[G][s] = v;
            }
    }

    const int ha0 = stg_addr(ln,      8 * grp);
    const int ha1 = stg_addr(ln, 32 + 8 * grp);
    const int ha2 = stg_addr(ln, 64 + 8 * grp);
    const int ha3 = stg_addr(ln, 96 + 8 * grp);
    int hwr[4];
    #pragma unroll
    for (int r = 0; r < 4; ++r) hwr[r] = stg_addr((grp << 2) + r, n);

    h16* hbuf0 = smem;           // 2048 halfs
    h16* hbuf1 = smem + 2048;
    const h16* prelane = pre + (size_t)b * 8192 + wave * 1024 + lane * 16;
    unsigned* myflags = flags + b * 32;

    // wait for chunk 0
    if (tid == 0)
        while (__hip_atomic_load(&myflags[0], __ATOMIC_ACQUIRE,
                                 __HIP_MEMORY_SCOPE_AGENT) == 0)
            __builtin_amdgcn_s_sleep(8);
    __syncthreads();
    __threadfence();

    // zero h(0); prime accA = preact(0); fill 2-deep prefetch
    *(half4v*)&hbuf0[tid << 2] = (half4v)0;
    f32x4 accA[4], accB[4];
    uint4 ph0, ph1, pn0, pn1;
    {
        const uint4* q0 = (const uint4*)(prelane);
        uint4 a0 = q0[0], a1 = q0[1];
        CVTACC(accA, a0, a1)
        const uint4* q1 = (const uint4*)(prelane + TSTRIDE);
        ph0 = q1[0]; ph1 = q1[1];
        const uint4* q2 = (const uint4*)(prelane + 2 * TSTRIDE);
        pn0 = q2[0]; pn1 = q2[1];
    }
    __syncthreads();

    f32x2 cst01 = {0.f, 0.f};
    f32x2 cst23 = {0.f, 0.f};
    const f32x2 one2 = {1.f, 1.f};
    const f32x2 sg2  = {SCALE_G, SCALE_G};

#define CSTEP(RD, WR, tcur, ACCC, ACCN)                                         \
  {                                                                             \
    /* pre-barrier: ACCN = preact(tcur+1); prefetch preact(tcur+3) */           \
    CVTACC(ACCN, ph0, ph1)                                                      \
    ph0 = pn0; ph1 = pn1;                                                       \
    {                                                                           \
        const int tld = ((tcur) + 3 < TSEQ) ? (tcur) + 3 : TSEQ - 1;            \
        const uint4* q = (const uint4*)(prelane + (size_t)tld * TSTRIDE);       \
        pn0 = q[0]; pn1 = q[1];                                                 \
    }                                                                           \
    __syncthreads();                                                            \
    half8v ah0 = *(const half8v*)&RD[ha0];                                      \
    half8v ah1 = *(const half8v*)&RD[ha1];                                      \
    half8v ah2 = *(const half8v*)&RD[ha2];                                      \
    half8v ah3 = *(const half8v*)&RD[ha3];                                      \
    /* k-major over g,i,f: same-acc dependency distance = 3 */                  \
    ACCC[0] = MFMA16(ah0, bh[0][0], ACCC[0]);                                   \
    ACCC[1] = MFMA16(ah0, bh[1][0], ACCC[1]);                                   \
    ACCC[2] = MFMA16(ah0, bh[2][0], ACCC[2]);                                   \
    ACCC[0] = MFMA16(ah1, bh[0][1], ACCC[0]);                                   \
    ACCC[1] = MFMA16(ah1, bh[1][1], ACCC[1]);                                   \
    ACCC[2] = MFMA16(ah1, bh[2][1], ACCC[2]);                                   \
    ACCC[0] = MFMA16(ah2, bh[0][2], ACCC[0]);                                   \
    ACCC[1] = MFMA16(ah2, bh[1][2], ACCC[1]);                                   \
    ACCC[2] = MFMA16(ah2, bh[2][2], ACCC[2]);                                   \
    ACCC[0] = MFMA16(ah3, bh[0][3], ACCC[0]);                                   \
    ACCC[1] = MFMA16(ah3, bh[1][3], ACCC[1]);                                   \
    ACCC[2] = MFMA16(ah3, bh[2][3], ACCC[2]);                                   \
    /* o-chain: drains under the packed c-math below */                         \
    ACCC[3] = MFMA16(ah0, bh[3][0], ACCC[3]);                                   \
    ACCC[3] = MFMA16(ah1, bh[3][1], ACCC[3]);                                   \
    ACCC[3] = MFMA16(ah2, bh[3][2], ACCC[3]);                                   \
    ACCC[3] = MFMA16(ah3, bh[3][3], ACCC[3]);                                   \
    f32x2 yc0, yc1;                                                             \
    CMATH(ACCC, 0, cst01, yc0)                                                  \
    CMATH(ACCC, 1, cst23, yc1)                                                  \
    h16* hw = WR;                                                               \
    HMATH(ACCC, 0, yc0)                                                         \
    HMATH(ACCC, 1, yc1)                                                         \
  }

    for (int t = 0; t < TSEQ; t += 2) {
        if ((t & 15) == 0) {
            const int cn = (t >> 4) + 1;
            if (tid == 0 && cn < 32)
                while (__hip_atomic_load(&myflags[cn], __ATOMIC_ACQUIRE,
                                         __HIP_MEMORY_SCOPE_AGENT) == 0)
                    __builtin_amdgcn_s_sleep(8);
            __syncthreads();
            __threadfence();
        }
        CSTEP(hbuf0, hbuf1, t,     accA, accB)
        CSTEP(hbuf1, hbuf0, t + 1, accB, accA)
    }
#undef CSTEP

    __syncthreads();
    // final h is in hbuf0
    if (tid < BM * NCLS) {
        const int m = tid / NCLS;
        const int cls = tid - m * NCLS;
        float s = bp[cls];
        #pragma unroll 8
        for (int k = 0; k < H; ++k) {
            float hvv = (float)hbuf0[stg_addr(m, k)];
            s += hvv * Wph[k * NCLS + cls];
        }
        out[(size_t)(b0 + m) * NCLS + cls] = s;
    }
}

// ============================================================================
// Fallback: round-11 kernel (verbatim) for when ws_size is insufficient.
// ============================================================================
__global__ __launch_bounds__(NTHREADS, 2)
void lstm_persist_fb(const float* __restrict__ x,
                  const float* __restrict__ Wgx, const float* __restrict__ Wgh,
                  const float* __restrict__ Wix, const float* __restrict__ Wih,
                  const float* __restrict__ Wfx, const float* __restrict__ Wfh,
                  const float* __restrict__ Wox, const float* __restrict__ Woh,
                  const float* __restrict__ Wph,
                  const float* __restrict__ bg, const float* __restrict__ bi,
                  const float* __restrict__ bfg, const float* __restrict__ bo,
                  const float* __restrict__ bp,
                  float* __restrict__ out)
{
    __shared__ __align__(16) h16 hbuf[2][H * BM];
    __shared__ __align__(16) h16 xbuf[2][DIN * BM];

    const int tid  = threadIdx.x;
    const int wave = tid >> 6;
    const int lane = tid & 63;
    const int grp  = lane >> 4;
    const int ln   = lane & 15;
    const int b0   = blockIdx.x * BM;
    const int n    = (wave << 4) + ln;

    half8v bx[4][2];
    half8v bh[4][4];
    f32x4  bias_c[4];
    {
        const float* WX[4] = {Wgx, Wix, Wfx, Wox};
        const float* WH[4] = {Wgh, Wih, Wfh, Woh};
        const float* BB[4] = {bg, bi, bfg, bo};
        const float  SC[4] = {SCALE_G, SCALE_S, SCALE_S, SCALE_S};
        #pragma unroll
        for (int G = 0; G < 4; ++G) {
            #pragma unroll
            for (int s = 0; s < 2; ++s) {
                half8v v;
                #pragma unroll
                for (int q = 0; q < 8; ++q)
                    v[q] = (h16)(WX[G][(32*s + 8*grp + q) * H + n] * SC[G]);
                bx[G][s] = v;
            }
            #pragma unroll
            for (int s = 0; s < 4; ++s) {
                half8v v;
                #pragma unroll
                for (int q = 0; q < 8; ++q)
                    v[q] = (h16)(WH[G][(32*s + 8*grp + q) * H + n] * SC[G]);
                bh[G][s] = v;
            }
            const float bb = BB[G][n] * SC[G];
            bias_c[G] = (f32x4){bb, bb, bb, bb};
        }
    }

    const int ha0 = stg_addr(ln,      8 * grp);
    const int ha1 = stg_addr(ln, 32 + 8 * grp);
    const int ha2 = stg_addr(ln, 64 + 8 * grp);
    const int ha3 = stg_addr(ln, 96 + 8 * grp);
    const int xa0 = ha0;
    const int xa1 = ha1;
    int hwr[4];
    #pragma unroll
    for (int r = 0; r < 4; ++r) hwr[r] = stg_addr((grp << 2) + r, n);

    const int xm  = tid >> 5;
    const int xk0 = (tid & 31) << 1;
    const int xwr = stg_addr(xm, xk0);
    const float* xrow = x + (size_t)(b0 + xm) * TSEQ * DIN + xk0;

    const f32x2 one2 = {1.f, 1.f};
    const f32x2 sg2  = {SCALE_G, SCALE_G};

    *(half4v*)&hbuf[0][tid << 2] = (half4v)0;
    {
        f32x2 x0 = *(const f32x2*)xrow;
        *(half2v*)&xbuf[0][xwr] =
            __builtin_bit_cast(half2v, __builtin_amdgcn_cvt_pkrtz(x0[0], x0[1]));
    }
    __syncthreads();

    f32x4 accA[4], accB[4];
    {
        half8v xf0 = *(const half8v*)&xbuf[0][xa0];
        half8v xf1 = *(const half8v*)&xbuf[0][xa1];
        #pragma unroll
        for (int G = 0; G < 4; ++G) {
            accA[G] = MFMA16(xf0, bx[G][0], bias_c[G]);
            accA[G] = MFMA16(xf1, bx[G][1], accA[G]);
        }
    }
    __syncthreads();

    f32x2 xhold, xnew;
    {
        f32x2 x1 = *(const f32x2*)(xrow + DIN);
        *(half2v*)&xbuf[0][xwr] =
            __builtin_bit_cast(half2v, __builtin_amdgcn_cvt_pkrtz(x1[0], x1[1]));
        xhold = *(const f32x2*)(xrow + 2 * DIN);
        xnew  = *(const f32x2*)(xrow + 3 * DIN);
    }
    __syncthreads();

    f32x2 cst01 = {0.f, 0.f};
    f32x2 cst23 = {0.f, 0.f};

#define STEP(p_, tcur, ACCC, ACCN)                                              \
  {                                                                             \
    half8v xf0 = *(const half8v*)&xbuf[p_][xa0];                                \
    half8v xf1 = *(const half8v*)&xbuf[p_][xa1];                                \
    *(half2v*)&xbuf[p_ ^ 1][xwr] =                                              \
        __builtin_bit_cast(half2v, __builtin_amdgcn_cvt_pkrtz(xhold[0], xhold[1])); \
    xhold = xnew;                                                               \
    const int tpre = ((tcur) + 4 < TSEQ) ? (tcur) + 4 : TSEQ - 1;               \
    xnew = *(const f32x2*)(xrow + (size_t)tpre * DIN);                          \
    _Pragma("unroll")                                                           \
    for (int G = 0; G < 4; ++G) {                                               \
        ACCN[G] = MFMA16(xf0, bx[G][0], bias_c[G]);                             \
        ACCN[G] = MFMA16(xf1, bx[G][1], ACCN[G]);                               \
    }                                                                           \
    __syncthreads();                                                            \
    half8v ah0 = *(const half8v*)&hbuf[p_][ha0];                                \
    half8v ah1 = *(const half8v*)&hbuf[p_][ha1];                                \
    half8v ah2 = *(const half8v*)&hbuf[p_][ha2];                                \
    half8v ah3 = *(const half8v*)&hbuf[p_][ha3];                                \
    ACCC[0] = MFMA16(ah0, bh[0][0], ACCC[0]);                                   \
    ACCC[1] = MFMA16(ah0, bh[1][0], ACCC[1]);                                   \
    ACCC[2] = MFMA16(ah0, bh[2][0], ACCC[2]);                                   \
    ACCC[0] = MFMA16(ah1, bh[0][1], ACCC[0]);                                   \
    ACCC[1] = MFMA16(ah1, bh[1][1], ACCC[1]);                                   \
    ACCC[2] = MFMA16(ah1, bh[2][1], ACCC[2]);                                   \
    ACCC[0] = MFMA16(ah2, bh[0][2], ACCC[0]);                                   \
    ACCC[1] = MFMA16(ah2, bh[1][2], ACCC[1]);                                   \
    ACCC[2] = MFMA16(ah2, bh[2][2], ACCC[2]);                                   \
    ACCC[0] = MFMA16(ah3, bh[0][3], ACCC[0]);                                   \
    ACCC[1] = MFMA16(ah3, bh[1][3], ACCC[1]);                                   \
    ACCC[2] = MFMA16(ah3, bh[2][3], ACCC[2]);                                   \
    ACCC[3] = MFMA16(ah0, bh[3][0], ACCC[3]);                                   \
    ACCC[3] = MFMA16(ah1, bh[3][1], ACCC[3]);                                   \
    ACCC[3] = MFMA16(ah2, bh[3][2], ACCC[3]);                                   \
    ACCC[3] = MFMA16(ah3, bh[3][3], ACCC[3]);                                   \
    f32x2 yc0, yc1;                                                             \
    CMATH(ACCC, 0, cst01, yc0)                                                  \
    CMATH(ACCC, 1, cst23, yc1)                                                  \
    h16* hw = hbuf[p_ ^ 1];                                                     \
    HMATH(ACCC, 0, yc0)                                                         \
    HMATH(ACCC, 1, yc1)                                                         \
  }

    for (int t = 0; t < TSEQ; t += 2) {
        STEP(0, t,     accA, accB)
        STEP(1, t + 1, accB, accA)
    }
#undef STEP

    __syncthreads();
    if (tid < BM * NCLS) {
        const int m = tid / NCLS;
        const int cls = tid - m * NCLS;
        float s = bp[cls];
        #pragma unroll 8
        for (int k = 0; k < H; ++k) {
            float hvv = (float)hbuf[0][stg_addr(m, k)];
            s += hvv * Wph[k * NCLS + cls];
        }
        out[(size_t)(b0 + m) * NCLS + cls] = s;
    }
}

extern "C" void kernel_launch(void* const* d_in, const int* in_sizes, int n_in,
                              void* d_out, int out_size, void* d_ws, size_t ws_size,
                              hipStream_t stream) {
    (void)in_sizes; (void)n_in; (void)out_size;
    const size_t PRE_BYTES  = (size_t)TSEQ * TSTRIDE * 2;   // 512 MB
    const size_t FLAG_BYTES = 8192;
    if (ws_size >= PRE_BYTES + FLAG_BYTES) {
        hipMemsetAsync(d_ws, 0, FLAG_BYTES, stream);
        lstm_fused<<<dim3(NCONS + NPROD), dim3(NTHREADS), 0, stream>>>(
            (const float*)d_in[0],
            (const float*)d_in[1], (const float*)d_in[2],
            (const float*)d_in[3], (const float*)d_in[4],
            (const float*)d_in[5], (const float*)d_in[6],
            (const float*)d_in[7], (const float*)d_in[8],
            (const float*)d_in[9],
            (const float*)d_in[10], (const float*)d_in[11],
            (const float*)d_in[12], (const float*)d_in[13],
            (const float*)d_in[14],
            (float*)d_out,
            (h16*)((char*)d_ws + FLAG_BYTES), (unsigned*)d_ws);
    } else {
        lstm_persist_fb<<<dim3(BATCH / BM), dim3(NTHREADS), 0, stream>>>(
            (const float*)d_in[0],
            (const float*)d_in[1], (const float*)d_in[2],
            (const float*)d_in[3], (const float*)d_in[4],
            (const float*)d_in[5], (const float*)d_in[6],
            (const float*)d_in[7], (const float*)d_in[8],
            (const float*)d_in[9],
            (const float*)d_in[10], (const float*)d_in[11],
            (const float*)d_in[12], (const float*)d_in[13],
            (const float*)d_in[14],
            (float*)d_out);
    }
}